// Round 1
// baseline (1599.808 us; speedup 1.0000x reference)
//
#include <hip/hip_runtime.h>

#define N_MSG 8192
#define DIM 256
#define KS 5
#define THRESH 0.2f
#define N_TEMPORAL (2*(N_MSG-1))            // 16382
#define N_EDGES (N_TEMPORAL + N_MSG*KS)     // 57342
#define ATTR_OFF (2*N_EDGES)                // 114684
#define VALID_OFF (ATTR_OFF + N_EDGES*64)   // 3784572
#define NCHUNK 4
#define CHUNK 2048
#define TI 64
#define TJ 64
#define TK 64

// Insert (v, j) into descending-sorted top-5 (ties: lower index first).
__device__ __forceinline__ void ins5(float v, int j, float (&vv)[KS], int (&xx)[KS]) {
    float cv = v; int cj = j;
#pragma unroll
    for (int k = 0; k < KS; ++k) {
        bool b = (cv > vv[k]) || (cv == vv[k] && cj < xx[k]);
        float tv = b ? vv[k] : cv; int tj = b ? xx[k] : cj;
        vv[k] = b ? cv : vv[k];    xx[k] = b ? cj : xx[k];
        cv = tv; cj = tj;
    }
}

// ---------------- Kernel A: L2-normalize rows ----------------
__global__ void normalize_k(const float* __restrict__ emb, float* __restrict__ out) {
    int row = blockIdx.x;
    int t = threadIdx.x;
    float x = emb[(size_t)row * DIM + t];
    float ss = x * x;
#pragma unroll
    for (int off = 32; off > 0; off >>= 1) ss += __shfl_down(ss, off);
    __shared__ float ws[4];
    if ((t & 63) == 0) ws[t >> 6] = ss;
    __syncthreads();
    float tot = ws[0] + ws[1] + ws[2] + ws[3];
    float nrm = fmaxf(sqrtf(tot), 1e-12f);
    out[(size_t)row * DIM + t] = x / nrm;
}

// ---------------- Kernel B: tiled sim + partial top-5 ----------------
__global__ __launch_bounds__(256)
void topk_partial_k(const float* __restrict__ embn,
                    float* __restrict__ pval, int* __restrict__ pidx) {
    const int bi = blockIdx.x;            // 0..127  (row tile)
    const int bc = blockIdx.y;            // 0..3    (j chunk)
    const int i0 = bi * TI;
    const int c0 = bc * CHUNK;
    if (c0 > i0 + (TI - 3)) return;       // no candidate j in this chunk for any row
    const int jend = min(c0 + CHUNK, i0 + TI - 2);  // exclusive; j <= i0+61

    const int tid = threadIdx.x;
    const int tx = tid & 15, ty = tid >> 4;

    __shared__ union {
        struct { float a[TK][TI + 4]; float b[TK][TJ + 4]; } st;   // k-major
        struct { float v[256][4][KS]; int x[256][4][KS]; } mg;
    } u;

    float v5[4][KS]; int x5[4][KS];
#pragma unroll
    for (int m = 0; m < 4; ++m)
#pragma unroll
        for (int k = 0; k < KS; ++k) { v5[m][k] = -1e30f; x5[m][k] = -1; }

    for (int jt = c0; jt < jend; jt += TJ) {
        float acc[4][4];
#pragma unroll
        for (int m = 0; m < 4; ++m)
#pragma unroll
            for (int n = 0; n < 4; ++n) acc[m][n] = 0.0f;

        for (int kt = 0; kt < DIM; kt += TK) {
            __syncthreads();
            {
                int r  = tid >> 2;
                int cb = (tid & 3) * 4;
                const float* gA = embn + (size_t)(i0 + r) * DIM + kt + cb;
                int jr = jt + r; if (jr > N_MSG - 1) jr = N_MSG - 1;
                const float* gB = embn + (size_t)jr * DIM + kt + cb;
#pragma unroll
                for (int q = 0; q < 4; ++q) {
                    float4 fa = *(const float4*)(gA + q * 16);
                    float4 fb = *(const float4*)(gB + q * 16);
                    int kl = cb + q * 16;
                    u.st.a[kl + 0][r] = fa.x; u.st.a[kl + 1][r] = fa.y;
                    u.st.a[kl + 2][r] = fa.z; u.st.a[kl + 3][r] = fa.w;
                    u.st.b[kl + 0][r] = fb.x; u.st.b[kl + 1][r] = fb.y;
                    u.st.b[kl + 2][r] = fb.z; u.st.b[kl + 3][r] = fb.w;
                }
            }
            __syncthreads();
#pragma unroll
            for (int k = 0; k < TK; ++k) {
                float4 av = *(const float4*)(&u.st.a[k][ty * 4]);
                float4 bv = *(const float4*)(&u.st.b[k][tx * 4]);
                float A4[4] = {av.x, av.y, av.z, av.w};
                float B4[4] = {bv.x, bv.y, bv.z, bv.w};
#pragma unroll
                for (int m = 0; m < 4; ++m)
#pragma unroll
                    for (int n = 0; n < 4; ++n)
                        acc[m][n] = fmaf(A4[m], B4[n], acc[m][n]);
            }
        }
        // fold tile results into per-thread top-5
#pragma unroll
        for (int m = 0; m < 4; ++m) {
            int i = i0 + ty * 4 + m;
#pragma unroll
            for (int n = 0; n < 4; ++n) {
                int j = jt + tx * 4 + n;
                float v = acc[m][n];
                if (v > THRESH && j <= i - 2) ins5(v, j, v5[m], x5[m]);
            }
        }
    }

    // block-level merge: 16 threads (tx) per row
    __syncthreads();
#pragma unroll
    for (int m = 0; m < 4; ++m)
#pragma unroll
        for (int k = 0; k < KS; ++k) { u.mg.v[tid][m][k] = v5[m][k]; u.mg.x[tid][m][k] = x5[m][k]; }
    __syncthreads();

    if (tid < TI) {
        int row = tid;
        int tyr = row >> 2, mr = row & 3;
        float fv[KS]; int fx[KS];
#pragma unroll
        for (int k = 0; k < KS; ++k) { fv[k] = -1e30f; fx[k] = -1; }
        for (int t2 = 0; t2 < 16; ++t2) {
            int src = tyr * 16 + t2;
#pragma unroll
            for (int k = 0; k < KS; ++k) {
                float v = u.mg.v[src][mr][k];
                if (v > THRESH) ins5(v, u.mg.x[src][mr][k], fv, fx);
            }
        }
        int i = i0 + row;
        size_t base = ((size_t)i * NCHUNK + bc) * KS;
#pragma unroll
        for (int k = 0; k < KS; ++k) { pval[base + k] = fv[k]; pidx[base + k] = fx[k]; }
    }
}

// ---------------- Kernel C: merge chunks, write semantic edge_index/valid ----------------
__global__ void merge_out_k(const float* __restrict__ pval, const int* __restrict__ pidx,
                            float* __restrict__ out) {
    int i = blockIdx.x * 256 + threadIdx.x;
    if (i >= N_MSG) return;
    float fv[KS]; int fx[KS];
#pragma unroll
    for (int k = 0; k < KS; ++k) { fv[k] = -1e30f; fx[k] = -1; }
    int i0 = i & ~(TI - 1);
    for (int c = 0; c < NCHUNK; ++c) {
        if (c * CHUNK > i0 + (TI - 3)) break;   // chunk never written / no candidates
        size_t base = ((size_t)i * NCHUNK + c) * KS;
#pragma unroll
        for (int k = 0; k < KS; ++k) {
            float v = pval[base + k];
            if (v > THRESH) ins5(v, pidx[base + k], fv, fx);
        }
    }
    int cnt = 0;
#pragma unroll
    for (int k = 0; k < KS; ++k) cnt += (fv[k] > THRESH) ? 1 : 0;
#pragma unroll
    for (int k = 0; k < KS; ++k) {
        int e = N_TEMPORAL + i * KS + k;
        bool val = (k < cnt);
        out[e]            = val ? (float)fx[k] : -1.0f;
        out[N_EDGES + e]  = val ? (float)i     : -1.0f;
        out[VALID_OFF + e] = val ? 1.0f : 0.0f;
    }
}

// ---------------- Kernel D: edge_attr for all edges + temporal index/valid ----------------
__global__ void attr_out_k(const float* __restrict__ table, float* __restrict__ out) {
    int idx = blockIdx.x * 256 + threadIdx.x;
    int e = idx >> 6, lane = idx & 63;
    if (e >= N_EDGES) return;
    float a;
    if (e < N_TEMPORAL) {
        a = table[lane];
        if (lane == 0) {
            int i = e >> 1;
            float src, dst;
            if (e & 1) { src = (float)(i + 1); dst = (float)i; }
            else       { src = (float)i;       dst = (float)(i + 1); }
            out[e]             = src;
            out[N_EDGES + e]   = dst;
            out[VALID_OFF + e] = 1.0f;
        }
    } else {
        float vld = out[VALID_OFF + e];
        a = table[64 + lane] * vld;
    }
    out[ATTR_OFF + (size_t)e * 64 + lane] = a;
}

extern "C" void kernel_launch(void* const* d_in, const int* in_sizes, int n_in,
                              void* d_out, int out_size, void* d_ws, size_t ws_size,
                              hipStream_t stream) {
    const float* emb   = (const float*)d_in[0];
    const float* table = (const float*)d_in[1];
    float* out = (float*)d_out;

    size_t embn_elems = (size_t)N_MSG * DIM;                 // 2,097,152 floats
    size_t part_elems = (size_t)N_MSG * NCHUNK * KS;         //   163,840
    size_t need_bytes = (embn_elems + 2 * part_elems) * 4;   // ~9.7 MB

    float* scratch;
    if (ws_size >= need_bytes) scratch = (float*)d_ws;
    else scratch = out + ATTR_OFF;   // carve from attr region; attr_out_k overwrites it last
    float* embn = scratch;
    float* pval = scratch + embn_elems;
    int*   pidx = (int*)(pval + part_elems);

    normalize_k<<<N_MSG, 256, 0, stream>>>(emb, embn);
    topk_partial_k<<<dim3(N_MSG / TI, NCHUNK), 256, 0, stream>>>(embn, pval, pidx);
    merge_out_k<<<(N_MSG + 255) / 256, 256, 0, stream>>>(pval, pidx, out);
    attr_out_k<<<((size_t)N_EDGES * 64 + 255) / 256, 256, 0, stream>>>(table, out);
}

// Round 2
// 248.212 us; speedup vs baseline: 6.4453x; 6.4453x over previous
//
#include <hip/hip_runtime.h>

#define N_MSG 8192
#define DIM 256
#define KS 5
#define THRESH 0.2f
#define N_TEMPORAL (2*(N_MSG-1))            // 16382
#define N_EDGES (N_TEMPORAL + N_MSG*KS)     // 57342
#define ATTR_OFF (2*N_EDGES)                // 114684
#define VALID_OFF (ATTR_OFF + N_EDGES*64)   // 3784572
#define BM 128
#define BN 128
#define BK 32
#define NTILE 64                             // N_MSG / BM
#define NBLOCKS (NTILE*(NTILE+1)/2)          // 2080
#define CAP 64

// Insert (v, j) into descending-sorted top-5 (ties: lower index first).
__device__ __forceinline__ void ins5(float v, int j, float (&vv)[KS], int (&xx)[KS]) {
    float cv = v; int cj = j;
#pragma unroll
    for (int k = 0; k < KS; ++k) {
        bool b = (cv > vv[k]) || (cv == vv[k] && cj < xx[k]);
        float tv = b ? vv[k] : cv; int tj = b ? xx[k] : cj;
        vv[k] = b ? cv : vv[k];    xx[k] = b ? cj : xx[k];
        cv = tv; cj = tj;
    }
}

// ---------------- Kernel A: L2-normalize rows (+ zero per-row counters) ----
__global__ void normalize_k(const float* __restrict__ emb, float* __restrict__ out,
                            int* __restrict__ cnt) {
    int row = blockIdx.x;
    int t = threadIdx.x;
    if (t == 0) cnt[row] = 0;
    float x = emb[(size_t)row * DIM + t];
    float ss = x * x;
#pragma unroll
    for (int off = 32; off > 0; off >>= 1) ss += __shfl_down(ss, off);
    __shared__ float ws[4];
    if ((t & 63) == 0) ws[t >> 6] = ss;
    __syncthreads();
    float tot = ws[0] + ws[1] + ws[2] + ws[3];
    float nrm = fmaxf(sqrtf(tot), 1e-12f);
    out[(size_t)row * DIM + t] = x / nrm;
}

// ---------------- Kernel B: triangular tiled sim + atomic candidate append --
__global__ __launch_bounds__(256)
void sim_topk_k(const float* __restrict__ embn, int* __restrict__ cnt,
                float* __restrict__ cval, int* __restrict__ cidx) {
    __shared__ __align__(16) float As[BK][BM + 4];
    __shared__ __align__(16) float Bs[BK][BN + 4];

    // triangular decode: block t -> (bi, bj), bj <= bi
    int t = blockIdx.x;
    int bi = (int)((sqrtf(8.0f * (float)t + 1.0f) - 1.0f) * 0.5f);
    while ((bi + 1) * (bi + 2) / 2 <= t) ++bi;
    while (bi * (bi + 1) / 2 > t) --bi;
    int bj = t - bi * (bi + 1) / 2;

    const int i0 = bi * BM, j0 = bj * BN;
    const int tid = threadIdx.x;
    const int tx = tid & 15, ty = tid >> 4;
    const int lr = tid >> 3, lk = (tid & 7) * 4;

    float acc[8][8];
#pragma unroll
    for (int m = 0; m < 8; ++m)
#pragma unroll
        for (int n = 0; n < 8; ++n) acc[m][n] = 0.0f;

    for (int kt = 0; kt < DIM; kt += BK) {
        __syncthreads();
#pragma unroll
        for (int q = 0; q < 4; ++q) {
            int r = lr + 32 * q;
            float4 fa = *(const float4*)(embn + (size_t)(i0 + r) * DIM + kt + lk);
            float4 fb = *(const float4*)(embn + (size_t)(j0 + r) * DIM + kt + lk);
            As[lk + 0][r] = fa.x; As[lk + 1][r] = fa.y;
            As[lk + 2][r] = fa.z; As[lk + 3][r] = fa.w;
            Bs[lk + 0][r] = fb.x; Bs[lk + 1][r] = fb.y;
            Bs[lk + 2][r] = fb.z; Bs[lk + 3][r] = fb.w;
        }
        __syncthreads();
#pragma unroll 4
        for (int k = 0; k < BK; ++k) {
            float4 a0 = *(const float4*)(&As[k][ty * 8]);
            float4 a1 = *(const float4*)(&As[k][ty * 8 + 4]);
            float4 b0 = *(const float4*)(&Bs[k][tx * 8]);
            float4 b1 = *(const float4*)(&Bs[k][tx * 8 + 4]);
            float A8[8] = {a0.x, a0.y, a0.z, a0.w, a1.x, a1.y, a1.z, a1.w};
            float B8[8] = {b0.x, b0.y, b0.z, b0.w, b1.x, b1.y, b1.z, b1.w};
#pragma unroll
            for (int m = 0; m < 8; ++m)
#pragma unroll
                for (int n = 0; n < 8; ++n)
                    acc[m][n] = fmaf(A8[m], B8[n], acc[m][n]);
        }
    }

    // epilogue: rare atomic append of candidates above threshold
#pragma unroll
    for (int m = 0; m < 8; ++m) {
        int i = i0 + ty * 8 + m;
#pragma unroll
        for (int n = 0; n < 8; ++n) {
            int j = j0 + tx * 8 + n;
            float v = acc[m][n];
            if (v > THRESH && j <= i - 2) {
                int c = atomicAdd(&cnt[i], 1);
                if (c < CAP) { cval[(size_t)i * CAP + c] = v; cidx[(size_t)i * CAP + c] = j; }
            }
        }
    }
}

// ---------------- Kernel C: per-row top-5 sort, write semantic index/valid --
__global__ void merge_out_k(const int* __restrict__ cnt, const float* __restrict__ cval,
                            const int* __restrict__ cidx, float* __restrict__ out) {
    int i = blockIdx.x * 256 + threadIdx.x;
    if (i >= N_MSG) return;
    float fv[KS]; int fx[KS];
#pragma unroll
    for (int k = 0; k < KS; ++k) { fv[k] = -1e30f; fx[k] = -1; }
    int nc = cnt[i]; if (nc > CAP) nc = CAP;
    for (int c = 0; c < nc; ++c)
        ins5(cval[(size_t)i * CAP + c], cidx[(size_t)i * CAP + c], fv, fx);
    int valid_cnt = (nc < KS) ? nc : KS;
#pragma unroll
    for (int k = 0; k < KS; ++k) {
        int e = N_TEMPORAL + i * KS + k;
        bool val = (k < valid_cnt);
        out[e]             = val ? (float)fx[k] : -1.0f;
        out[N_EDGES + e]   = val ? (float)i     : -1.0f;
        out[VALID_OFF + e] = val ? 1.0f : 0.0f;
    }
}

// ---------------- Kernel D: edge_attr for all edges + temporal index/valid --
__global__ void attr_out_k(const float* __restrict__ table, float* __restrict__ out) {
    int idx = blockIdx.x * 256 + threadIdx.x;
    int e = idx >> 6, lane = idx & 63;
    if (e >= N_EDGES) return;
    float a;
    if (e < N_TEMPORAL) {
        a = table[lane];
        if (lane == 0) {
            int i = e >> 1;
            float src, dst;
            if (e & 1) { src = (float)(i + 1); dst = (float)i; }
            else       { src = (float)i;       dst = (float)(i + 1); }
            out[e]             = src;
            out[N_EDGES + e]   = dst;
            out[VALID_OFF + e] = 1.0f;
        }
    } else {
        float vld = out[VALID_OFF + e];
        a = table[64 + lane] * vld;
    }
    out[ATTR_OFF + (size_t)e * 64 + lane] = a;
}

extern "C" void kernel_launch(void* const* d_in, const int* in_sizes, int n_in,
                              void* d_out, int out_size, void* d_ws, size_t ws_size,
                              hipStream_t stream) {
    const float* emb   = (const float*)d_in[0];
    const float* table = (const float*)d_in[1];
    float* out = (float*)d_out;

    size_t embn_elems = (size_t)N_MSG * DIM;        // 2,097,152 floats (8.39 MB)
    size_t cand_elems = (size_t)N_MSG * CAP;        //   524,288 floats (2 MB) x2
    size_t cnt_elems  = N_MSG;
    size_t need_bytes = (embn_elems + 2 * cand_elems + cnt_elems) * 4;  // ~12.5 MB

    float* scratch;
    if (ws_size >= need_bytes) scratch = (float*)d_ws;
    else scratch = out + ATTR_OFF;   // carve from attr region (14.68 MB); attr written last
    float* embn = scratch;
    float* cval = scratch + embn_elems;
    int*   cidx = (int*)(cval + cand_elems);
    int*   cnt  = (int*)(cidx + cand_elems);

    normalize_k<<<N_MSG, 256, 0, stream>>>(emb, embn, cnt);
    sim_topk_k<<<NBLOCKS, 256, 0, stream>>>(embn, cnt, cval, cidx);
    merge_out_k<<<(N_MSG + 255) / 256, 256, 0, stream>>>(cnt, cval, cidx, out);
    attr_out_k<<<((size_t)N_EDGES * 64 + 255) / 256, 256, 0, stream>>>(table, out);
}

// Round 3
// 77.503 us; speedup vs baseline: 20.6419x; 3.2026x over previous
//
#include <hip/hip_runtime.h>

#define N_MSG 8192
#define DIM 256
#define KS 5
#define THRESH 0.2f
#define FILT 0.196f                          // bf16-filter margin (~16 sigma)
#define N_TEMPORAL (2*(N_MSG-1))             // 16382
#define N_EDGES (N_TEMPORAL + N_MSG*KS)      // 57342
#define ATTR_OFF (2*N_EDGES)                 // 114684
#define VALID_OFF (ATTR_OFF + N_EDGES*64)    // 3784572
#define BM 128
#define BN 128
#define NTILE (N_MSG / BM)                   // 64
#define NBLOCKS (NTILE*(NTILE+1)/2)          // 2080
#define CAP 32

typedef __bf16 bf16x8 __attribute__((ext_vector_type(8)));
typedef __bf16 bf16x4 __attribute__((ext_vector_type(4)));
typedef float  f32x4  __attribute__((ext_vector_type(4)));

__device__ __forceinline__ void gload_lds16(const void* g, void* l) {
    __builtin_amdgcn_global_load_lds(
        (const __attribute__((address_space(1))) void*)g,
        (__attribute__((address_space(3))) void*)l, 16, 0, 0);
}

// Insert (v, j) into descending-sorted top-5 (ties: lower index first).
__device__ __forceinline__ void ins5(float v, int j, float (&vv)[KS], int (&xx)[KS]) {
    float cv = v; int cj = j;
#pragma unroll
    for (int k = 0; k < KS; ++k) {
        bool b = (cv > vv[k]) || (cv == vv[k] && cj < xx[k]);
        float tv = b ? vv[k] : cv; int tj = b ? xx[k] : cj;
        vv[k] = b ? cv : vv[k];    xx[k] = b ? cj : xx[k];
        cv = tv; cj = tj;
    }
}

// ---- Kernel A: L2-normalize rows (fp32 + bf16 copy), zero counters -------
__global__ void normalize_k(const float* __restrict__ emb, float* __restrict__ embn,
                            __bf16* __restrict__ embh, int* __restrict__ cnt) {
    int lane = threadIdx.x & 63;
    int row = blockIdx.x * 4 + (threadIdx.x >> 6);
    const float4 x = *(const float4*)(emb + (size_t)row * DIM + lane * 4);
    float ss = x.x * x.x;
    ss = fmaf(x.y, x.y, ss); ss = fmaf(x.z, x.z, ss); ss = fmaf(x.w, x.w, ss);
#pragma unroll
    for (int off = 1; off <= 32; off <<= 1) ss += __shfl_xor(ss, off);
    float nrm = fmaxf(sqrtf(ss), 1e-12f);
    float4 y; y.x = x.x / nrm; y.y = x.y / nrm; y.z = x.z / nrm; y.w = x.w / nrm;
    *(float4*)(embn + (size_t)row * DIM + lane * 4) = y;
    bf16x4 h; h[0] = (__bf16)y.x; h[1] = (__bf16)y.y; h[2] = (__bf16)y.z; h[3] = (__bf16)y.w;
    *(bf16x4*)(embh + (size_t)row * DIM + lane * 4) = h;
    if (lane == 0) cnt[row] = 0;
}

// ---- Kernel B: MFMA bf16 sim over lower-triangle tiles + filtered append --
__global__ __launch_bounds__(256, 4)
void sim_filter_k(const __bf16* __restrict__ embh, int* __restrict__ cnt,
                  int* __restrict__ cidx) {
    // 16B-granule layout: granule g = kblk*128 + m  ->  row m, k-chunk kblk (8 bf16)
    __shared__ __align__(16) __bf16 As[BM * 32];
    __shared__ __align__(16) __bf16 Bs[BN * 32];

    int t = blockIdx.x;                       // triangular decode: bj <= bi
    int bi = (int)((sqrtf(8.0f * (float)t + 1.0f) - 1.0f) * 0.5f);
    while ((bi + 1) * (bi + 2) / 2 <= t) ++bi;
    while (bi * (bi + 1) / 2 > t) --bi;
    int bj = t - bi * (bi + 1) / 2;
    const int i0 = bi * BM, j0 = bj * BN;

    const int tid = threadIdx.x;
    const int lane = tid & 63;
    const int ws = tid >> 6;                  // wave id 0..3
    const int wm = ws >> 1, wn = ws & 1;      // 2x2 wave grid, 64x64 each
    const int lr = lane & 15, kb = lane >> 4;

    const int gm1 = tid & 127, gk1 = tid >> 7;        // granule tid
    const int gm2 = tid & 127, gk2 = (tid >> 7) + 2;  // granule tid+256

    f32x4 acc[4][4];
#pragma unroll
    for (int m = 0; m < 4; ++m)
#pragma unroll
        for (int n = 0; n < 4; ++n) { f32x4 z = {0.f, 0.f, 0.f, 0.f}; acc[m][n] = z; }

    for (int kt = 0; kt < DIM; kt += 32) {
        __syncthreads();
        gload_lds16(embh + (size_t)(i0 + gm1) * DIM + kt + gk1 * 8, &As[(size_t)tid * 8]);
        gload_lds16(embh + (size_t)(i0 + gm2) * DIM + kt + gk2 * 8, &As[((size_t)tid + 256) * 8]);
        gload_lds16(embh + (size_t)(j0 + gm1) * DIM + kt + gk1 * 8, &Bs[(size_t)tid * 8]);
        gload_lds16(embh + (size_t)(j0 + gm2) * DIM + kt + gk2 * 8, &Bs[((size_t)tid + 256) * 8]);
        __syncthreads();

        bf16x8 a[4], b[4];
#pragma unroll
        for (int f = 0; f < 4; ++f) {
            a[f] = *(const bf16x8*)&As[(kb * 128 + wm * 64 + f * 16 + lr) * 8];
            b[f] = *(const bf16x8*)&Bs[(kb * 128 + wn * 64 + f * 16 + lr) * 8];
        }
#pragma unroll
        for (int m = 0; m < 4; ++m)
#pragma unroll
            for (int n = 0; n < 4; ++n)
                acc[m][n] = __builtin_amdgcn_mfma_f32_16x16x32_bf16(a[m], b[n], acc[m][n], 0, 0, 0);
    }

    // epilogue: rare filtered atomic append (indices only; fp32 rescue later)
#pragma unroll
    for (int m = 0; m < 4; ++m) {
        int i = i0 + wm * 64 + m * 16 + kb * 4;
#pragma unroll
        for (int n = 0; n < 4; ++n) {
            int j = j0 + wn * 64 + n * 16 + lr;
#pragma unroll
            for (int r = 0; r < 4; ++r) {
                float v = acc[m][n][r];
                int ii = i + r;
                if (v > FILT && j <= ii - 2) {
                    int c = atomicAdd(&cnt[ii], 1);
                    if (c < CAP) cidx[(size_t)ii * CAP + c] = j;
                }
            }
        }
    }
}

// ---- Kernel C: fp32-exact rescue: recompute candidates, top-5, write ------
__global__ void rescue_k(const float* __restrict__ embn, const int* __restrict__ cnt,
                         const int* __restrict__ cidx, float* __restrict__ out) {
    int i = blockIdx.x;
    int lane = threadIdx.x;                   // 64 threads = 1 wave
    int nc = cnt[i]; if (nc > CAP) nc = CAP;

    float fv[KS]; int fx[KS];
#pragma unroll
    for (int k = 0; k < KS; ++k) { fv[k] = -1e30f; fx[k] = -1; }

    if (nc > 0) {
        const float4 a = *(const float4*)(embn + (size_t)i * DIM + lane * 4);
        for (int c = 0; c < nc; ++c) {
            int j = cidx[(size_t)i * CAP + c];
            const float4 b = *(const float4*)(embn + (size_t)j * DIM + lane * 4);
            float p = a.x * b.x;
            p = fmaf(a.y, b.y, p); p = fmaf(a.z, b.z, p); p = fmaf(a.w, b.w, p);
#pragma unroll
            for (int off = 1; off <= 32; off <<= 1) p += __shfl_xor(p, off);
            if (p > THRESH) ins5(p, j, fv, fx);   // identical on all lanes
        }
    }
    int vcnt = 0;
#pragma unroll
    for (int k = 0; k < KS; ++k) vcnt += (fv[k] > THRESH) ? 1 : 0;
    if (lane < KS) {
        int e = N_TEMPORAL + i * KS + lane;
        bool val = (lane < vcnt);
        out[e]             = val ? (float)fx[lane] : -1.0f;
        out[N_EDGES + e]   = val ? (float)i        : -1.0f;
        out[VALID_OFF + e] = val ? 1.0f : 0.0f;
    }
}

// ---- Kernel D: edge_attr (float4) + temporal index/valid ------------------
__global__ void attr_out_k(const float* __restrict__ table, float* __restrict__ out) {
    int idx = blockIdx.x * 256 + threadIdx.x;
    int e = idx >> 4, sub = idx & 15;
    if (e >= N_EDGES) return;
    float4 a4;
    if (e < N_TEMPORAL) {
        a4 = *(const float4*)(table + sub * 4);
        if (sub == 0) {
            int i = e >> 1;
            out[e]             = (e & 1) ? (float)(i + 1) : (float)i;
            out[N_EDGES + e]   = (e & 1) ? (float)i       : (float)(i + 1);
            out[VALID_OFF + e] = 1.0f;
        }
    } else {
        float vld = out[VALID_OFF + e];
        a4 = *(const float4*)(table + 64 + sub * 4);
        a4.x *= vld; a4.y *= vld; a4.z *= vld; a4.w *= vld;
    }
    *(float4*)(out + ATTR_OFF + (size_t)e * 64 + sub * 4) = a4;
}

extern "C" void kernel_launch(void* const* d_in, const int* in_sizes, int n_in,
                              void* d_out, int out_size, void* d_ws, size_t ws_size,
                              hipStream_t stream) {
    const float* emb   = (const float*)d_in[0];
    const float* table = (const float*)d_in[1];
    float* out = (float*)d_out;

    size_t embn_f  = (size_t)N_MSG * DIM;              // 2,097,152 floats (8.39 MB)
    size_t embh_f  = (size_t)N_MSG * DIM / 2;          // bf16 array = 4.19 MB
    size_t cidx_f  = (size_t)N_MSG * CAP;              // 1 MB
    size_t cnt_f   = N_MSG;                            // 32 KB
    size_t need_bytes = (embn_f + embh_f + cidx_f + cnt_f) * 4;  // ~13.7 MB

    float* scratch;
    if (ws_size >= need_bytes) scratch = (float*)d_ws;
    else scratch = out + ATTR_OFF;   // carve from attr region (14.68 MB); attr written last
    float*  embn = scratch;
    __bf16* embh = (__bf16*)(scratch + embn_f);
    int*    cidx = (int*)(scratch + embn_f + embh_f);
    int*    cnt  = (int*)(scratch + embn_f + embh_f + cidx_f);

    normalize_k<<<N_MSG / 4, 256, 0, stream>>>(emb, embn, embh, cnt);
    sim_filter_k<<<NBLOCKS, 256, 0, stream>>>(embh, cnt, cidx);
    rescue_k<<<N_MSG, 64, 0, stream>>>(embn, cnt, cidx, out);
    attr_out_k<<<((size_t)N_EDGES * 16 + 255) / 256, 256, 0, stream>>>(table, out);
}

// Round 4
// 67.014 us; speedup vs baseline: 23.8727x; 1.1565x over previous
//
#include <hip/hip_runtime.h>

#define N_MSG 8192
#define DIM 256
#define KS 5
#define THRESH 0.2f
#define FILT 0.196f                          // bf16-filter margin (~16 sigma)
#define N_TEMPORAL (2*(N_MSG-1))             // 16382
#define N_EDGES (N_TEMPORAL + N_MSG*KS)      // 57342
#define ATTR_OFF (2*N_EDGES)                 // 114684
#define VALID_OFF (ATTR_OFF + N_EDGES*64)    // 3784572
#define BM 128
#define NTILE (N_MSG / BM)                   // 64
#define NBLOCKS (NTILE*(NTILE+1)/2)          // 2080
#define CAP 32

typedef __bf16 bf16x8 __attribute__((ext_vector_type(8)));
typedef __bf16 bf16x4 __attribute__((ext_vector_type(4)));
typedef float  f32x4  __attribute__((ext_vector_type(4)));

__device__ __forceinline__ void gload_lds16(const void* g, void* l) {
    __builtin_amdgcn_global_load_lds(
        (const __attribute__((address_space(1))) void*)g,
        (__attribute__((address_space(3))) void*)l, 16, 0, 0);
}

// Insert (v, j) into descending-sorted top-5 (ties: lower index first).
__device__ __forceinline__ void ins5(float v, int j, float (&vv)[KS], int (&xx)[KS]) {
    float cv = v; int cj = j;
#pragma unroll
    for (int k = 0; k < KS; ++k) {
        bool b = (cv > vv[k]) || (cv == vv[k] && cj < xx[k]);
        float tv = b ? vv[k] : cv; int tj = b ? xx[k] : cj;
        vv[k] = b ? cv : vv[k];    xx[k] = b ? cj : xx[k];
        cv = tv; cj = tj;
    }
}

// ---- Kernel A: L2-normalize rows (fp32 + bf16 copy), zero counters -------
__global__ void normalize_k(const float* __restrict__ emb, float* __restrict__ embn,
                            __bf16* __restrict__ embh, int* __restrict__ cnt) {
    int lane = threadIdx.x & 63;
    int row = blockIdx.x * 4 + (threadIdx.x >> 6);
    const float4 x = *(const float4*)(emb + (size_t)row * DIM + lane * 4);
    float ss = x.x * x.x;
    ss = fmaf(x.y, x.y, ss); ss = fmaf(x.z, x.z, ss); ss = fmaf(x.w, x.w, ss);
#pragma unroll
    for (int off = 1; off <= 32; off <<= 1) ss += __shfl_xor(ss, off);
    float nrm = fmaxf(sqrtf(ss), 1e-12f);
    float4 y; y.x = x.x / nrm; y.y = x.y / nrm; y.z = x.z / nrm; y.w = x.w / nrm;
    *(float4*)(embn + (size_t)row * DIM + lane * 4) = y;
    bf16x4 h; h[0] = (__bf16)y.x; h[1] = (__bf16)y.y; h[2] = (__bf16)y.z; h[3] = (__bf16)y.w;
    *(bf16x4*)(embh + (size_t)row * DIM + lane * 4) = h;
    if (lane == 0) cnt[row] = 0;
}

// ---- Kernel B: MFMA bf16 sim, full-tile resident LDS, 2 staging phases ----
// LDS layout per half-K (128 k): row-major [128 rows][16 chunks of 16B],
// chunk slot = chunk ^ (row&7)  (both-sides swizzle; inverse applied on the
// coalesced global source so global_load_lds can write linearly).
__global__ __launch_bounds__(256, 2)
void sim_filter_k(const __bf16* __restrict__ embh, int* __restrict__ cnt,
                  int* __restrict__ cidx) {
    __shared__ __align__(16) __bf16 As[BM * 128];   // 32 KB
    __shared__ __align__(16) __bf16 Bs[BM * 128];   // 32 KB

    int t = blockIdx.x;                       // triangular decode: bj <= bi
    int bi = (int)((sqrtf(8.0f * (float)t + 1.0f) - 1.0f) * 0.5f);
    while ((bi + 1) * (bi + 2) / 2 <= t) ++bi;
    while (bi * (bi + 1) / 2 > t) --bi;
    int bj = t - bi * (bi + 1) / 2;
    const int i0 = bi * BM, j0 = bj * BM;

    const int tid = threadIdx.x;
    const int lane = tid & 63;
    const int ws = tid >> 6;                  // wave id 0..3
    const int wm = ws >> 1, wn = ws & 1;      // 2x2 wave grid, 64x64 each
    const int lr = lane & 15, kb = lane >> 4;

    f32x4 acc[4][4];
#pragma unroll
    for (int m = 0; m < 4; ++m)
#pragma unroll
        for (int n = 0; n < 4; ++n) { f32x4 z = {0.f, 0.f, 0.f, 0.f}; acc[m][n] = z; }

#pragma unroll
    for (int h = 0; h < 2; ++h) {
        if (h) __syncthreads();               // all reads of half0 done before overwrite
#pragma unroll
        for (int q = 0; q < 8; ++q) {
            int g = q * 256 + tid;            // granule 0..2047
            int row = g >> 4, s = g & 15;
            int sc = s ^ (row & 7);           // inverse swizzle on source chunk
            gload_lds16(embh + (size_t)(i0 + row) * DIM + h * 128 + sc * 8, &As[(size_t)g * 8]);
            gload_lds16(embh + (size_t)(j0 + row) * DIM + h * 128 + sc * 8, &Bs[(size_t)g * 8]);
        }
        __syncthreads();                      // compiler drains vmcnt before barrier

#pragma unroll
        for (int ks = 0; ks < 4; ++ks) {
            bf16x8 a[4], b[4];
#pragma unroll
            for (int f = 0; f < 4; ++f) {
                int ra = wm * 64 + f * 16 + lr;
                a[f] = *(const bf16x8*)&As[(size_t)ra * 128 + (((ks * 4 + kb) ^ (ra & 7)) << 3)];
                int rb = wn * 64 + f * 16 + lr;
                b[f] = *(const bf16x8*)&Bs[(size_t)rb * 128 + (((ks * 4 + kb) ^ (rb & 7)) << 3)];
            }
#pragma unroll
            for (int m = 0; m < 4; ++m)
#pragma unroll
                for (int n = 0; n < 4; ++n)
                    acc[m][n] = __builtin_amdgcn_mfma_f32_16x16x32_bf16(a[m], b[n], acc[m][n], 0, 0, 0);
        }
    }

    // epilogue: rare filtered atomic append (indices only; fp32 rescue later)
#pragma unroll
    for (int m = 0; m < 4; ++m) {
        int i = i0 + wm * 64 + m * 16 + kb * 4;
#pragma unroll
        for (int n = 0; n < 4; ++n) {
            int j = j0 + wn * 64 + n * 16 + lr;
#pragma unroll
            for (int r = 0; r < 4; ++r) {
                float v = acc[m][n][r];
                int ii = i + r;
                if (v > FILT && j <= ii - 2) {
                    int c = atomicAdd(&cnt[ii], 1);
                    if (c < CAP) cidx[(size_t)ii * CAP + c] = j;
                }
            }
        }
    }
}

// ---- Kernel C: fp32-exact rescue + (optionally fused) output writes -------
template<bool FUSE>
__global__ void rescue_k(const float* __restrict__ embn, const int* __restrict__ cnt,
                         const int* __restrict__ cidx, const float* __restrict__ table,
                         float* __restrict__ out) {
    int lane = threadIdx.x & 63;
    int i = blockIdx.x * 4 + (threadIdx.x >> 6);
    int nc = cnt[i]; if (nc > CAP) nc = CAP;

    float fv[KS]; int fx[KS];
#pragma unroll
    for (int k = 0; k < KS; ++k) { fv[k] = -1e30f; fx[k] = -1; }

    if (nc > 0) {
        const float4 a = *(const float4*)(embn + (size_t)i * DIM + lane * 4);
        for (int c = 0; c < nc; ++c) {
            int j = cidx[(size_t)i * CAP + c];
            const float4 b = *(const float4*)(embn + (size_t)j * DIM + lane * 4);
            float p = a.x * b.x;
            p = fmaf(a.y, b.y, p); p = fmaf(a.z, b.z, p); p = fmaf(a.w, b.w, p);
#pragma unroll
            for (int off = 1; off <= 32; off <<= 1) p += __shfl_xor(p, off);
            if (p > THRESH) ins5(p, j, fv, fx);   // identical on all lanes
        }
    }
    int vcnt = 0;
#pragma unroll
    for (int k = 0; k < KS; ++k) vcnt += (fv[k] > THRESH) ? 1 : 0;

    float tsem = FUSE ? table[64 + lane] : 0.0f;
#pragma unroll
    for (int k = 0; k < KS; ++k) {
        int e = N_TEMPORAL + i * KS + k;
        bool val = (k < vcnt);
        if (lane == 0) {
            out[e]             = val ? (float)fx[k] : -1.0f;
            out[N_EDGES + e]   = val ? (float)i     : -1.0f;
            out[VALID_OFF + e] = val ? 1.0f : 0.0f;
        }
        if (FUSE) out[ATTR_OFF + (size_t)e * 64 + lane] = val ? tsem : 0.0f;
    }
    if (FUSE) {
        if (i < N_MSG - 1) {
            float ttem = table[lane];
            int e0 = 2 * i;
            out[ATTR_OFF + (size_t)e0 * 64 + lane]       = ttem;
            out[ATTR_OFF + (size_t)(e0 + 1) * 64 + lane] = ttem;
            if (lane == 0) {
                out[e0]                 = (float)i;
                out[N_EDGES + e0]       = (float)(i + 1);
                out[VALID_OFF + e0]     = 1.0f;
                out[e0 + 1]             = (float)(i + 1);
                out[N_EDGES + e0 + 1]   = (float)i;
                out[VALID_OFF + e0 + 1] = 1.0f;
            }
        }
    }
}

// ---- Kernel D (fallback only, when scratch carved from attr region) -------
__global__ void attr_out_k(const float* __restrict__ table, float* __restrict__ out) {
    int idx = blockIdx.x * 256 + threadIdx.x;
    int e = idx >> 4, sub = idx & 15;
    if (e >= N_EDGES) return;
    float4 a4;
    if (e < N_TEMPORAL) {
        a4 = *(const float4*)(table + sub * 4);
        if (sub == 0) {
            int i = e >> 1;
            out[e]             = (e & 1) ? (float)(i + 1) : (float)i;
            out[N_EDGES + e]   = (e & 1) ? (float)i       : (float)(i + 1);
            out[VALID_OFF + e] = 1.0f;
        }
    } else {
        float vld = out[VALID_OFF + e];
        a4 = *(const float4*)(table + 64 + sub * 4);
        a4.x *= vld; a4.y *= vld; a4.z *= vld; a4.w *= vld;
    }
    *(float4*)(out + ATTR_OFF + (size_t)e * 64 + sub * 4) = a4;
}

extern "C" void kernel_launch(void* const* d_in, const int* in_sizes, int n_in,
                              void* d_out, int out_size, void* d_ws, size_t ws_size,
                              hipStream_t stream) {
    const float* emb   = (const float*)d_in[0];
    const float* table = (const float*)d_in[1];
    float* out = (float*)d_out;

    size_t embn_f  = (size_t)N_MSG * DIM;              // 2,097,152 floats (8.39 MB)
    size_t embh_f  = (size_t)N_MSG * DIM / 2;          // bf16 array = 4.19 MB
    size_t cidx_f  = (size_t)N_MSG * CAP;              // 1 MB
    size_t cnt_f   = N_MSG;                            // 32 KB
    size_t need_bytes = (embn_f + embh_f + cidx_f + cnt_f) * 4;  // ~13.7 MB

    bool have_ws = (ws_size >= need_bytes);
    float* scratch = have_ws ? (float*)d_ws
                             : out + ATTR_OFF;  // carve attr region; attr written last
    float*  embn = scratch;
    __bf16* embh = (__bf16*)(scratch + embn_f);
    int*    cidx = (int*)(scratch + embn_f + embh_f);
    int*    cnt  = (int*)(scratch + embn_f + embh_f + cidx_f);

    normalize_k<<<N_MSG / 4, 256, 0, stream>>>(emb, embn, embh, cnt);
    sim_filter_k<<<NBLOCKS, 256, 0, stream>>>(embh, cnt, cidx);
    if (have_ws) {
        rescue_k<true><<<N_MSG / 4, 256, 0, stream>>>(embn, cnt, cidx, table, out);
    } else {
        rescue_k<false><<<N_MSG / 4, 256, 0, stream>>>(embn, cnt, cidx, table, out);
        attr_out_k<<<((size_t)N_EDGES * 16 + 255) / 256, 256, 0, stream>>>(table, out);
    }
}